// Round 7
// baseline (228.055 us; speedup 1.0000x reference)
//
#include <hip/hip_runtime.h>
#include <hip/hip_bf16.h>

typedef __attribute__((ext_vector_type(8))) short short8;
typedef __attribute__((ext_vector_type(4))) float floatx4;
typedef __attribute__((ext_vector_type(16))) float floatx16;
typedef unsigned short ushortt;

#define LOG2E 1.4426950408889634f

__device__ __forceinline__ float fast_exp2(float x) {
    return __builtin_amdgcn_exp2f(x);      // raw v_exp_f32
}
__device__ __forceinline__ ushortt f2bf(float f) {
    unsigned int u = __float_as_uint(f);
    u += 0x7fffu + ((u >> 16) & 1u);
    return (ushortt)(u >> 16);
}
__device__ __forceinline__ unsigned int f2bf_pk(float a, float b) {
    float2 t; t.x = a; t.y = b;
    __hip_bfloat162 h = __float22bfloat162_rn(t);
    return *reinterpret_cast<unsigned int*>(&h);
}
__device__ __forceinline__ float bf2f(ushortt h) {
    return __uint_as_float(((unsigned int)h) << 16);
}

__device__ __forceinline__ float block_sum(float v, float* red) {
    #pragma unroll
    for (int off = 32; off > 0; off >>= 1) v += __shfl_down(v, off);
    int wid = threadIdx.x >> 6, ln = threadIdx.x & 63;
    __syncthreads();
    if (ln == 0) red[wid] = v;
    __syncthreads();
    return red[0] + red[1] + red[2] + red[3];
}

// ---------------------------------------------------------------------------
// sigma = ||W @ normalize(W^T u)|| + fused bf16 weight conversion.
// Phase-2 is row-per-thread dots (no per-row butterfly chains).
// ---------------------------------------------------------------------------
__global__ __launch_bounds__(256) void sigma_kernel(
    const float* __restrict__ Wf, const float* __restrict__ uf,
    const float* __restrict__ Wg, const float* __restrict__ ug,
    const float* __restrict__ Wh, const float* __restrict__ uh,
    const float* __restrict__ Wv, const float* __restrict__ uv,
    float* __restrict__ sig, ushortt* __restrict__ wqkv, ushortt* __restrict__ wvb) {
    __shared__ float tv[512];
    __shared__ float tvp[256];
    __shared__ float zpart[256];
    __shared__ float red[4];
    __shared__ float sbc;
    const int mat = blockIdx.x, tid = threadIdx.x;

    if (mat < 3) {  // W: [64][512]
        const float* W = (mat == 0) ? Wf : ((mat == 1) ? Wg : Wh);
        const float* u = (mat == 0) ? uf : ((mat == 1) ? ug : uh);
        for (int c = tid; c < 512; c += 256) {
            float s0 = 0.f;
            #pragma unroll 8
            for (int r = 0; r < 64; ++r) s0 += W[r * 512 + c] * u[r];
            tv[c] = s0;
        }
        __syncthreads();
        float p = tv[tid] * tv[tid] + tv[tid + 256] * tv[tid + 256];
        float nt2 = block_sum(p, red);
        float nt = fmaxf(sqrtf(nt2), 1e-12f);
        {
            int r = tid & 63, qq = tid >> 6;
            const float* Wr = W + r * 512 + qq * 128;
            const float* tq = tv + qq * 128;
            float part = 0.f;
            #pragma unroll 16
            for (int c = 0; c < 128; ++c) part += Wr[c] * tq[c];
            zpart[tid] = part;
        }
        __syncthreads();
        if (tid < 64) {
            float z = zpart[tid] + zpart[tid + 64] + zpart[tid + 128] + zpart[tid + 192];
            z = z * z;
            #pragma unroll
            for (int off = 32; off > 0; off >>= 1) z += __shfl_xor(z, off);
            if (tid == 0) {
                float sv = sqrtf(z) / nt;
                sig[mat] = sv;
                sbc = sv;
            }
        }
        __syncthreads();
        float inv = 1.0f / sbc;
        for (int idx = tid; idx < 32768; idx += 256)
            wqkv[mat * 32768 + idx] = f2bf(W[idx] * inv);
    } else {        // Wv: [512][64]
        const float* W = Wv; const float* u = uv;
        {
            int c = tid & 63, rs = tid >> 6;
            float s0 = 0.f;
            #pragma unroll 8
            for (int r = rs * 128; r < rs * 128 + 128; ++r) s0 += W[r * 64 + c] * u[r];
            tvp[tid] = s0;
        }
        __syncthreads();
        if (tid < 64) tv[tid] = tvp[tid] + tvp[tid + 64] + tvp[tid + 128] + tvp[tid + 192];
        __syncthreads();
        float t = (tid < 64) ? tv[tid] : 0.f;
        float nt2 = block_sum(t * t, red);
        float nt = fmaxf(sqrtf(nt2), 1e-12f);
        {
            const float* w1 = W + (size_t)tid * 64;
            const float* w2 = W + (size_t)(tid + 256) * 64;
            float z1 = 0.f, z2 = 0.f;
            #pragma unroll 8
            for (int c = 0; c < 64; ++c) {
                float tc = tv[c];
                z1 += w1[c] * tc;
                z2 += w2[c] * tc;
            }
            float zp = z1 * z1 + z2 * z2;
            float z2t = block_sum(zp, red);
            float inv = 1.0f / (sqrtf(z2t) / nt);
            if (tid == 0) sig[3] = sqrtf(z2t) / nt;
            for (int idx = tid; idx < 32768; idx += 256)
                wvb[idx] = f2bf(W[idx] * inv);
        }
    }
}

// ---------------------------------------------------------------------------
// QKV projection, 32-pixel tiles. XOR-swizzled LDS (all b128, conflict-free).
// Q stored pre-scaled by LOG2E. V stored transposed Vt[b][d][n].
// ---------------------------------------------------------------------------
__global__ __launch_bounds__(256, 4) void qkv_kernel(
    const float* __restrict__ x, const ushortt* __restrict__ wqkv,
    const float* __restrict__ bfv, const float* __restrict__ bgv,
    const float* __restrict__ bhv,
    ushortt* __restrict__ Qb, ushortt* __restrict__ Kb, ushortt* __restrict__ Vt) {
    __shared__ unsigned int xs[1120];
    const int tid = threadIdx.x;
    const int n0 = blockIdx.x * 32, b = blockIdx.y;
    const int lane = tid & 63, w = tid >> 6;
    const int strip = w & 1, ksel = w >> 1;
    const int q = lane >> 4, l15 = lane & 15;
    const int sn = tid & 31, sg = tid >> 5;

    floatx4 acc[6];
    #pragma unroll
    for (int kt = 0; kt < 6; ++kt) acc[kt] = (floatx4){0.f, 0.f, 0.f, 0.f};

    const float* xb = x + ((size_t)b * 512) * 4096 + n0 + sn;
    float2 pre[4];
    #pragma unroll
    for (int i = 0; i < 4; ++i) {
        int c = sg * 8 + 2 * i;
        pre[i].x = xb[(size_t)c * 4096];
        pre[i].y = xb[(size_t)(c + 1) * 4096];
    }

    for (int c0 = 0; c0 < 512; c0 += 64) {
        __syncthreads();
        {
            uint4 pk;
            pk.x = f2bf_pk(pre[0].x, pre[0].y);
            pk.y = f2bf_pk(pre[1].x, pre[1].y);
            pk.z = f2bf_pk(pre[2].x, pre[2].y);
            pk.w = f2bf_pk(pre[3].x, pre[3].y);
            *reinterpret_cast<uint4*>(&xs[sn * 32 + ((sg ^ (sn & 7)) << 2)]) = pk;
        }
        if (c0 + 64 < 512) {
            #pragma unroll
            for (int i = 0; i < 4; ++i) {
                int c = c0 + 64 + sg * 8 + 2 * i;
                pre[i].x = xb[(size_t)c * 4096];
                pre[i].y = xb[(size_t)(c + 1) * 4096];
            }
        }
        __syncthreads();
        const unsigned int* xr = &xs[(16 * strip + l15) * 32];
        #pragma unroll
        for (int kc = 0; kc < 2; ++kc) {
            union { uint4 v; short8 s8; } af;
            af.v = *reinterpret_cast<const uint4*>(&xr[((4 * kc + q) ^ (l15 & 7)) << 2]);
            #pragma unroll
            for (int kt = 0; kt < 6; ++kt) {
                short8 bb = *reinterpret_cast<const short8*>(
                    &wqkv[(size_t)(ksel * 96 + kt * 16 + l15) * 512 + c0 + kc * 32 + q * 8]);
                acc[kt] = __builtin_amdgcn_mfma_f32_16x16x32_bf16(af.s8, bb, acc[kt], 0, 0, 0);
            }
        }
    }

    const int nloc = n0 + 16 * strip + 4 * q;
    if (ksel == 0) {
        #pragma unroll
        for (int kt = 0; kt < 4; ++kt) {       // Q (exp2-domain)
            int k = kt * 16 + l15;
            float bb = bfv[k];
            #pragma unroll
            for (int r = 0; r < 4; ++r)
                Qb[((size_t)b * 4096 + nloc + r) * 64 + k] = f2bf((acc[kt][r] + bb) * LOG2E);
        }
        #pragma unroll
        for (int kt = 4; kt < 6; ++kt) {       // K rows 0..31
            int k = (kt - 4) * 16 + l15;
            float bb = bgv[k];
            #pragma unroll
            for (int r = 0; r < 4; ++r)
                Kb[((size_t)b * 4096 + nloc + r) * 64 + k] = f2bf(acc[kt][r] + bb);
        }
    } else {
        #pragma unroll
        for (int kt = 0; kt < 2; ++kt) {       // K rows 32..63
            int k = 32 + kt * 16 + l15;
            float bb = bgv[k];
            #pragma unroll
            for (int r = 0; r < 4; ++r)
                Kb[((size_t)b * 4096 + nloc + r) * 64 + k] = f2bf(acc[kt][r] + bb);
        }
    }
    __syncthreads();
    if (ksel == 1) {                           // V -> LDS [d][n/2] (stride 17 dwords)
        #pragma unroll
        for (int kt = 2; kt < 6; ++kt) {
            int d = (kt - 2) * 16 + l15;
            float bb = bhv[d];
            int base = d * 17 + 8 * strip + 2 * q;
            xs[base]     = f2bf_pk(acc[kt][0] + bb, acc[kt][1] + bb);
            xs[base + 1] = f2bf_pk(acc[kt][2] + bb, acc[kt][3] + bb);
        }
    }
    __syncthreads();
    {
        int d = tid >> 2, sgg = tid & 3;
        uint4 vv;
        vv.x = xs[d * 17 + sgg * 4 + 0]; vv.y = xs[d * 17 + sgg * 4 + 1];
        vv.z = xs[d * 17 + sgg * 4 + 2]; vv.w = xs[d * 17 + sgg * 4 + 3];
        *reinterpret_cast<uint4*>(&Vt[((size_t)b * 64 + d) * 4096 + n0 + sgg * 8]) = vv;
    }
}

// ---------------------------------------------------------------------------
// Flash attention, 32x32x16 MFMA, 128 keys per barrier round (2 subtiles):
// halves barriers and amortizes softmax fixed costs. XOR-swizzled b128 LDS.
// ---------------------------------------------------------------------------
__global__ __launch_bounds__(256, 3) void attn_kernel(
    const ushortt* __restrict__ Qb, const ushortt* __restrict__ Kb,
    const ushortt* __restrict__ Vt, ushortt* __restrict__ Opart,
    float2* __restrict__ ml, ushortt* __restrict__ Ob, int KB) {
    __shared__ unsigned int smem[8192];
    // staging: KS = [0..4096) 128 rows x 32 dw; VS = [4096..8192) 64 rows x 64 dw
    // merge:   OM = [0..4160) 64x65 f32; MLm = [4160..4288); MLl = [4288..4416)
    const int tid = threadIdx.x;
    const int n0 = blockIdx.x * 64, b = blockIdx.y, s = blockIdx.z;
    const int lane = tid & 63, w = tid >> 6;
    const int qh = w & 1, kh = w >> 1;
    const int l31 = lane & 31, h = lane >> 5;

    const ushortt* Kg = Kb + (size_t)b * 4096 * 64;
    const ushortt* Vg = Vt + (size_t)b * 64 * 4096;

    short8 bq[4];
    {
        const ushortt* Qg = Qb + ((size_t)b * 4096 + n0 + 32 * qh + l31) * 64;
        #pragma unroll
        for (int kc = 0; kc < 4; ++kc)
            bq[kc] = *reinterpret_cast<const short8*>(Qg + kc * 16 + 8 * h);
    }

    floatx16 ot0 = {}, ot1 = {};
    float m_i = -1e30f, l_i = 0.f;

    const int krow = tid >> 1, khalf = tid & 1;   // K staging: row 0..127, 4 chunks
    const int vrow = tid >> 2, vq = tid & 3;      // V staging: d 0..63, 4 chunks
    const int kbeg = s * KB;

    for (int kp = 0; kp < KB; kp += 2) {
        const int nb = (kbeg + kp) * 64;
        __syncthreads();
        {   // stage 128-key K tile + V tile, swizzled b128
            const ushortt* kpg = Kg + (size_t)(nb + krow) * 64 + khalf * 32;
            #pragma unroll
            for (int j = 0; j < 4; ++j) {
                int ch = 4 * khalf + j;
                uint4 v = *reinterpret_cast<const uint4*>(kpg + j * 8);
                *reinterpret_cast<uint4*>(&smem[krow * 32 + ((ch ^ (krow & 7)) << 2)]) = v;
            }
            const ushortt* vpg = Vg + (size_t)vrow * 4096 + nb + vq * 32;
            #pragma unroll
            for (int j = 0; j < 4; ++j) {
                int ch = 4 * vq + j;
                uint4 v = *reinterpret_cast<const uint4*>(vpg + j * 8);
                int sw = (ch & 8) | ((ch & 7) ^ (vrow & 7));
                *reinterpret_cast<uint4*>(&smem[4096 + vrow * 64 + (sw << 2)]) = v;
            }
        }
        __syncthreads();

        // S^T for both subtiles (keys 32kh+l31 and 64+32kh+l31)
        floatx16 st0 = {}, st1 = {};
        {
            int r0 = 32 * kh + l31;
            const unsigned int* kr0 = &smem[r0 * 32];
            const unsigned int* kr1 = &smem[(64 + r0) * 32];
            const int esw = r0 & 7;   // (64+r0)&7 == r0&7
            #pragma unroll
            for (int kc = 0; kc < 4; ++kc) {
                union { uint4 v; short8 s8; } a0, a1;
                a0.v = *reinterpret_cast<const uint4*>(&kr0[((2 * kc + h) ^ esw) << 2]);
                a1.v = *reinterpret_cast<const uint4*>(&kr1[((2 * kc + h) ^ esw) << 2]);
                st0 = __builtin_amdgcn_mfma_f32_32x32x16_bf16(a0.s8, bq[kc], st0, 0, 0, 0);
                st1 = __builtin_amdgcn_mfma_f32_32x32x16_bf16(a1.s8, bq[kc], st1, 0, 0, 0);
            }
        }

        // online softmax over 64 scores for column q=l31
        float mx = fmaxf(st0[0], st1[0]);
        #pragma unroll
        for (int r = 1; r < 16; ++r) mx = fmaxf(mx, fmaxf(st0[r], st1[r]));
        mx = fmaxf(mx, __shfl_xor(mx, 32));
        if (__any(mx > m_i)) {
            float mn = fmaxf(m_i, mx);
            float alpha = fast_exp2(m_i - mn);
            m_i = mn;
            l_i *= alpha;
            #pragma unroll
            for (int r = 0; r < 16; ++r) { ot0[r] *= alpha; ot1[r] *= alpha; }
        }
        float rs = 0.f;
        #pragma unroll
        for (int r = 0; r < 16; ++r) {
            st0[r] = fast_exp2(st0[r] - m_i); rs += st0[r];
            st1[r] = fast_exp2(st1[r] - m_i); rs += st1[r];
        }
        rs += __shfl_xor(rs, 32);
        l_i += rs;

        // P: C-layout -> B-operand frags, in-register (per subtile)
        unsigned int pka[8], pkb[8], spa[8], spb[8];
        #pragma unroll
        for (int i = 0; i < 8; ++i) {
            pka[i] = f2bf_pk(st0[2 * i], st0[2 * i + 1]);
            pkb[i] = f2bf_pk(st1[2 * i], st1[2 * i + 1]);
        }
        #pragma unroll
        for (int i = 0; i < 8; ++i) {
            spa[i] = (unsigned int)__shfl_xor((int)pka[i], 32);
            spb[i] = (unsigned int)__shfl_xor((int)pkb[i], 32);
        }
        union { unsigned int u[4]; short8 s8; } pA0, pA1, pB0, pB1;
        pA0.u[0] = h ? spa[2] : pka[0]; pA0.u[1] = h ? spa[3] : pka[1];
        pA0.u[2] = h ? pka[2] : spa[0]; pA0.u[3] = h ? pka[3] : spa[1];
        pA1.u[0] = h ? spa[6] : pka[4]; pA1.u[1] = h ? spa[7] : pka[5];
        pA1.u[2] = h ? pka[6] : spa[4]; pA1.u[3] = h ? pka[7] : spa[5];
        pB0.u[0] = h ? spb[2] : pkb[0]; pB0.u[1] = h ? spb[3] : pkb[1];
        pB0.u[2] = h ? pkb[2] : spb[0]; pB0.u[3] = h ? pkb[3] : spb[1];
        pB1.u[0] = h ? spb[6] : pkb[4]; pB1.u[1] = h ? spb[7] : pkb[5];
        pB1.u[2] = h ? pkb[6] : spb[4]; pB1.u[3] = h ? pkb[7] : spb[5];

        // O^T += V^T P : 2 subtiles x 2 key-chunks x 2 d-strips
        const int esw = l31 & 7;
        const unsigned int* vb0 = &smem[4096 + l31 * 64];
        const unsigned int* vb1 = &smem[4096 + (32 + l31) * 64];
        #pragma unroll
        for (int t = 0; t < 2; ++t) {
            #pragma unroll
            for (int c = 0; c < 2; ++c) {
                int c16 = 8 * t + 4 * kh + 2 * c + h;
                int sw = ((c16 & 8) | ((c16 & 7) ^ esw)) << 2;
                short8 pb = t ? (c ? pB1.s8 : pB0.s8) : (c ? pA1.s8 : pA0.s8);
                union { uint4 v; short8 s8; } af;
                af.v = *reinterpret_cast<const uint4*>(&vb0[sw]);
                ot0 = __builtin_amdgcn_mfma_f32_32x32x16_bf16(af.s8, pb, ot0, 0, 0, 0);
                af.v = *reinterpret_cast<const uint4*>(&vb1[sw]);
                ot1 = __builtin_amdgcn_mfma_f32_32x32x16_bf16(af.s8, pb, ot1, 0, 0, 0);
            }
        }
    }

    // ---- merge kh halves ----
    __syncthreads();
    if (h == 0) {
        smem[4160 + w * 32 + l31] = __float_as_uint(m_i);
        smem[4288 + w * 32 + l31] = __float_as_uint(l_i);
    }
    __syncthreads();
    int pw = 2 * (1 - kh) + qh;
    float m2 = __uint_as_float(smem[4160 + pw * 32 + l31]);
    float l2 = __uint_as_float(smem[4288 + pw * 32 + l31]);
    float mstar = fmaxf(m_i, m2);
    float wself = fast_exp2(m_i - mstar);
    float w2 = fast_exp2(m2 - mstar);
    float lm = wself * l_i + w2 * l2;
    float sc = (gridDim.z == 1) ? (wself / lm) : wself;
    if (gridDim.z > 1 && kh == 0 && h == 0) {
        float2 v; v.x = mstar; v.y = lm;
        ml[((size_t)s * 4 + b) * 4096 + n0 + 32 * qh + l31] = v;
    }
    float* om = reinterpret_cast<float*>(smem);
    if (kh == 0) {
        #pragma unroll
        for (int r = 0; r < 16; ++r) {
            int d0 = (r & 3) + 8 * (r >> 2) + 4 * h;
            om[(32 * qh + l31) * 65 + d0] = sc * ot0[r];
            om[(32 * qh + l31) * 65 + 32 + d0] = sc * ot1[r];
        }
    }
    __syncthreads();
    if (kh == 1) {
        #pragma unroll
        for (int r = 0; r < 16; ++r) {
            int d0 = (r & 3) + 8 * (r >> 2) + 4 * h;
            om[(32 * qh + l31) * 65 + d0] += sc * ot0[r];
            om[(32 * qh + l31) * 65 + 32 + d0] += sc * ot1[r];
        }
    }
    __syncthreads();
    {
        int qq = tid >> 2, dsg = tid & 3;
        unsigned int pkk[8];
        #pragma unroll
        for (int j = 0; j < 8; ++j)
            pkk[j] = f2bf_pk(om[qq * 65 + dsg * 16 + 2 * j], om[qq * 65 + dsg * 16 + 2 * j + 1]);
        ushortt* base = (gridDim.z == 1)
            ? (Ob + ((size_t)b * 4096 + n0) * 64)
            : (Opart + (((size_t)s * 4 + b) * 4096 + n0) * 64);
        uint4* d4 = reinterpret_cast<uint4*>(base + (size_t)qq * 64 + dsg * 16);
        uint4 o0; o0.x = pkk[0]; o0.y = pkk[1]; o0.z = pkk[2]; o0.w = pkk[3];
        uint4 o1; o1.x = pkk[4]; o1.y = pkk[5]; o1.z = pkk[6]; o1.w = pkk[7];
        d4[0] = o0; d4[1] = o1;
    }
}

// ---------------------------------------------------------------------------
// Merge KV-split partials (bf16 Opart, exp2-domain m).
// ---------------------------------------------------------------------------
__global__ __launch_bounds__(256) void combine_kernel(
    const ushortt* __restrict__ Opart, const float2* __restrict__ ml,
    ushortt* __restrict__ Ob, int S) {
    const int tid = threadIdx.x;
    const int n0 = blockIdx.x * 64, b = blockIdx.y;
    const int row = n0 + (tid >> 2), dseg = tid & 3;
    float2 mls[4];
    float m = -1e30f;
    for (int s = 0; s < S; ++s) {
        mls[s] = ml[((size_t)s * 4 + b) * 4096 + row];
        m = fmaxf(m, mls[s].x);
    }
    float wgt[4], denom = 0.f;
    for (int s = 0; s < S; ++s) {
        wgt[s] = fast_exp2(mls[s].x - m);
        denom += wgt[s] * mls[s].y;
    }
    float inv = 1.0f / denom;
    float acc[16];
    #pragma unroll
    for (int j = 0; j < 16; ++j) acc[j] = 0.f;
    for (int s = 0; s < S; ++s) {
        const uint4* op = reinterpret_cast<const uint4*>(
            Opart + (((size_t)s * 4 + b) * 4096 + row) * 64 + dseg * 16);
        union { uint4 v; ushortt hh[8]; } u0, u1;
        u0.v = op[0]; u1.v = op[1];
        float ww = wgt[s];
        #pragma unroll
        for (int j = 0; j < 8; ++j) {
            acc[j] += ww * bf2f(u0.hh[j]);
            acc[8 + j] += ww * bf2f(u1.hh[j]);
        }
    }
    union { uint4 u[2]; unsigned int ww[8]; } pkv;
    #pragma unroll
    for (int j = 0; j < 8; ++j) pkv.ww[j] = f2bf_pk(acc[2 * j] * inv, acc[2 * j + 1] * inv);
    uint4* dst = reinterpret_cast<uint4*>(Ob + ((size_t)b * 4096 + row) * 64 + dseg * 16);
    dst[0] = pkv.u[0]; dst[1] = pkv.u[1];
}

// ---------------------------------------------------------------------------
// out = gamma*(Wv_sn O + bv) + x
// ---------------------------------------------------------------------------
__global__ __launch_bounds__(256) void proj_kernel(
    const ushortt* __restrict__ Ob, const ushortt* __restrict__ wvb,
    const float* __restrict__ bv, const float* __restrict__ gamma,
    const float* __restrict__ x, float* __restrict__ out) {
    const int tid = threadIdx.x;
    const int n0 = blockIdx.y * 64, c0 = blockIdx.x * 64, b = blockIdx.z;
    const int w = tid >> 6, lane = tid & 63, q = lane >> 4, l15 = lane & 15;

    short8 a0 = *reinterpret_cast<const short8*>(&wvb[(size_t)(c0 + 16 * w + l15) * 64 + q * 8]);
    short8 a1 = *reinterpret_cast<const short8*>(&wvb[(size_t)(c0 + 16 * w + l15) * 64 + 32 + q * 8]);
    floatx4 acc[4];
    #pragma unroll
    for (int t = 0; t < 4; ++t) acc[t] = (floatx4){0.f, 0.f, 0.f, 0.f};
    #pragma unroll
    for (int t = 0; t < 4; ++t) {
        const ushortt* ob = Ob + ((size_t)b * 4096 + n0 + 16 * t + l15) * 64;
        short8 b0 = *reinterpret_cast<const short8*>(ob + q * 8);
        short8 b1 = *reinterpret_cast<const short8*>(ob + 32 + q * 8);
        acc[t] = __builtin_amdgcn_mfma_f32_16x16x32_bf16(a0, b0, acc[t], 0, 0, 0);
        acc[t] = __builtin_amdgcn_mfma_f32_16x16x32_bf16(a1, b1, acc[t], 0, 0, 0);
    }
    float gm = gamma[0];
    #pragma unroll
    for (int t = 0; t < 4; ++t) {
        #pragma unroll
        for (int r = 0; r < 4; ++r) {
            int c = c0 + 16 * w + 4 * q + r;
            int n = n0 + 16 * t + l15;
            size_t idx = ((size_t)(b * 512 + c)) * 4096 + n;
            out[idx] = gm * (acc[t][r] + bv[c]) + x[idx];
        }
    }
}

// ---------------------------------------------------------------------------
extern "C" void kernel_launch(void* const* d_in, const int* in_sizes, int n_in,
                              void* d_out, int out_size, void* d_ws, size_t ws_size,
                              hipStream_t stream) {
    const float* x   = (const float*)d_in[0];
    const float* Wf  = (const float*)d_in[1];
    const float* bf_ = (const float*)d_in[2];
    const float* Wg  = (const float*)d_in[3];
    const float* bg_ = (const float*)d_in[4];
    const float* Wh  = (const float*)d_in[5];
    const float* bh_ = (const float*)d_in[6];
    const float* Wv  = (const float*)d_in[7];
    const float* bv_ = (const float*)d_in[8];
    const float* uf  = (const float*)d_in[9];
    const float* ug  = (const float*)d_in[10];
    const float* uh  = (const float*)d_in[11];
    const float* uv  = (const float*)d_in[12];
    const float* gm  = (const float*)d_in[13];
    float* out = (float*)d_out;

    char* ws = (char*)d_ws;
    float*   sig   = (float*)ws;                         // 256 B
    ushortt* wqkv  = (ushortt*)(ws + 256);               // 196608
    ushortt* wvb   = (ushortt*)(ws + 196864);            // 65536
    ushortt* Qb    = (ushortt*)(ws + 262400);            // 2 MB
    ushortt* Kb    = (ushortt*)(ws + 2359552);           // 2 MB
    ushortt* Vt    = (ushortt*)(ws + 4456704);           // 2 MB  [b][d][n]
    ushortt* Ob    = (ushortt*)(ws + 6553856);           // 2 MB
    float2*  ml    = (float2*)(ws + 8651008);            // 512 KB (S=4)
    ushortt* Opart = (ushortt*)(ws + 9175296);           // 8 MB bf16 (S=4)

    int S = (ws_size >= (size_t)17563904) ? 4 : 1;

    sigma_kernel<<<4, 256, 0, stream>>>(Wf, uf, Wg, ug, Wh, uh, Wv, uv, sig, wqkv, wvb);
    qkv_kernel<<<dim3(128, 4), 256, 0, stream>>>(x, wqkv, bf_, bg_, bh_, Qb, Kb, Vt);
    attn_kernel<<<dim3(64, 4, S), 256, 0, stream>>>(Qb, Kb, Vt, Opart, ml, Ob, 64 / S);
    if (S > 1) combine_kernel<<<dim3(64, 4), 256, 0, stream>>>(Opart, ml, Ob, S);
    proj_kernel<<<dim3(8, 64, 4), 256, 0, stream>>>(Ob, wvb, bv_, gm, x, out);
}